// Round 11
// baseline (186.993 us; speedup 1.0000x reference)
//
#include <hip/hip_runtime.h>
#include <hip/hip_bf16.h>

// GAT attention aggregator, fused. B=20000, N=32, D=128, H=256, O=128.
// R11: async staging via global_load_lds (zero staging VGPRs, all loads in
// flight). neibs staged as f32 in LDS (pre-swizzled GLOBAL source address,
// linear LDS dest per m173); f32->bf16 conversion happens at MFMA-fragment
// build (v_cvt_pk). MB=2 nodes/block, 10000 blocks, 256 thr. Aggregation
// reads f32 (better numerics). LDS 38.1 KB -> 4 blocks/CU.

#define BB 20000
#define NN 32
#define DD 128
#define HH 256
#define OO 128
#define MB 2

typedef __bf16 bf16x8 __attribute__((ext_vector_type(8)));
typedef __bf16 bf16x4 __attribute__((ext_vector_type(4)));
typedef float f32x4 __attribute__((ext_vector_type(4)));

template<int CTRL>
__device__ __forceinline__ float dpp_add(float v) {
    int r = __builtin_amdgcn_update_dpp(0, __builtin_bit_cast(int, v), CTRL, 0xF, 0xF, true);
    return v + __builtin_bit_cast(float, r);
}
// lane 15 of each 16-lane row ends with the row sum
__device__ __forceinline__ float red16(float v) {
    v = dpp_add<0x111>(v);
    v = dpp_add<0x112>(v);
    v = dpp_add<0x114>(v);
    v = dpp_add<0x118>(v);
    return v;
}

__global__ void prep_weights(const float* __restrict__ Watt,
                             const float* __restrict__ Wfcx,
                             const float* __restrict__ Wfcn,
                             __bf16* __restrict__ WaT,
                             __bf16* __restrict__ WcT) {
    int idx = blockIdx.x * 256 + threadIdx.x;   // 0..65535
    int half = idx >> 15;
    int j = idx & 32767;
    int c = j >> 7, k = j & 127;
    if (half == 0) {
        WaT[j] = (__bf16)Watt[k * HH + c];       // WaT[h][k] = W_att[k][h]
    } else {
        float wv = (c < OO) ? Wfcx[k * OO + c] : Wfcn[k * OO + (c - OO)];
        WcT[j] = (__bf16)wv;                     // WcT[c][k]
    }
}

__launch_bounds__(256, 4)
__global__ void gat_fused(const float* __restrict__ x,
                          const float* __restrict__ neibs,
                          const float* __restrict__ a,
                          const __bf16* __restrict__ WaT,
                          const __bf16* __restrict__ WcT,
                          float* __restrict__ out) {
    __shared__ float  nb32[64 * 128];            // 32 KB f32 neib rows, col-XOR-swizzled
    __shared__ __bf16 xagg[16 * 128];            //  4 KB bf16 [x0,x1,agg0,agg1,junk...]
    __shared__ float  e_part[4][80];             //  1.28 KB

    const int tid = threadIdx.x;
    const int w   = tid >> 6;      // wave 0..3
    const int l   = tid & 63;
    const int lr  = l & 15;
    const int lg  = l >> 4;
    const int q   = w >> 1;        // local node (0/1) this wave serves
    const int dh  = w & 1;         // d-half for aggregation
    const int b0  = blockIdx.x * MB;
    char* nb = (char*)nb32;
    char* xb = (char*)xagg;

    // ---- async stage: 8 global_load_lds(16B) per wave, all in flight ----
    // LDS linear dest: wave w covers rows [w*16, w*16+16). Source address is
    // pre-swizzled so LDS[row][cb] = global[row][cb ^ ((row&15)<<5)].
    {
        const char* gbase = (const char*)neibs + (size_t)b0 * NN * DD * 4;
        const int cb = 16 * (l & 31);
#pragma unroll
        for (int j = 0; j < 8; ++j) {
            const int rl  = w * 16 + 2 * j + (l >> 5);      // rl&15 = 2j + (l>>5)
            const int src = rl * 512 + (cb ^ (((2 * j + (l >> 5)) & 15) << 5));
            __builtin_amdgcn_global_load_lds(
                (const __attribute__((address_space(1))) void*)(gbase + src),
                (__attribute__((address_space(3))) void*)(nb + w * 8192 + j * 1024),
                16, 0, 0);
        }
    }
    // x rows 0..1 of xagg (threads 0..63), reg path (tiny)
    if (tid < 64) {
        f32x4 v = *((const f32x4*)(x + (size_t)b0 * DD) + tid);
        int row = tid >> 5, c2 = 8 * (tid & 31);
        bf16x4 s = { (__bf16)v.x, (__bf16)v.y, (__bf16)v.z, (__bf16)v.w };
        *(bf16x4*)(xb + row * 256 + (c2 ^ ((row & 7) << 4))) = s;
    }

    // W_att panel + a (L2-resident; latency hides under staging)
    bf16x8 bw[4][4];
    float aX[4], aN[4];
#pragma unroll
    for (int c4 = 0; c4 < 4; ++c4) {
        int col = w * 64 + c4 * 16 + lr;
#pragma unroll
        for (int ks = 0; ks < 4; ++ks)
            bw[c4][ks] = *(const bf16x8*)(WaT + (size_t)col * 128 + ks * 32 + lg * 8);
        aX[c4] = a[col];
        aN[c4] = a[HH + col];
    }
    __syncthreads();                              // B1 (drains vmcnt: gll done)

    // ---- score: rt 0..3 neib rows (f32->bf16 on the fly), rt 4 = x tile ----
#pragma unroll
    for (int rt = 0; rt < 5; ++rt) {
        bf16x8 af[4];
        if (rt < 4) {
#pragma unroll
            for (int ks = 0; ks < 4; ++ks) {
                const int row = rt * 16 + lr;     // row&15 = lr
                const char* p = nb + row * 512 + ((ks * 128 + lg * 32) ^ (lr << 5));
                f32x4 u = *(const f32x4*)p;
                f32x4 v = *(const f32x4*)(p + 16);
                af[ks] = (bf16x8){ (__bf16)u.x, (__bf16)u.y, (__bf16)u.z, (__bf16)u.w,
                                   (__bf16)v.x, (__bf16)v.y, (__bf16)v.z, (__bf16)v.w };
            }
        } else {
#pragma unroll
            for (int ks = 0; ks < 4; ++ks)
                af[ks] = *(const bf16x8*)(xb + lr * 256 + ((ks * 64 + lg * 16) ^ ((lr & 7) << 4)));
        }
        f32x4 acc[4];
#pragma unroll
        for (int c4 = 0; c4 < 4; ++c4) acc[c4] = (f32x4){0.f, 0.f, 0.f, 0.f};
#pragma unroll
        for (int ks = 0; ks < 4; ++ks)
#pragma unroll
            for (int c4 = 0; c4 < 4; ++c4)
                acc[c4] = __builtin_amdgcn_mfma_f32_16x16x32_bf16(af[ks], bw[c4][ks], acc[c4], 0, 0, 0);
        float ep[4] = {0.f, 0.f, 0.f, 0.f};
#pragma unroll
        for (int c4 = 0; c4 < 4; ++c4) {
            float av = (rt == 4) ? aX[c4] : aN[c4];
#pragma unroll
            for (int i = 0; i < 4; ++i) {
                float v = acc[c4][i];
                float lv = fmaxf(v, 0.f) + 0.01f * fminf(v, 0.f);
                ep[i] = fmaf(lv, av, ep[i]);
            }
        }
#pragma unroll
        for (int i = 0; i < 4; ++i) ep[i] = red16(ep[i]);
        if (lr == 15) {
            f32x4 st = { ep[0], ep[1], ep[2], ep[3] };
            *(f32x4*)((char*)&e_part[w][0] + rt * 64 + lg * 16) = st;
        }
    }
    __syncthreads();                              // B2: e_part complete

    // ---- softmax over 32 neighbors (in-wave; 32-lane halves duplicate) ----
    float att;
    {
        const int nl = l & 31;
        const int idx = q * 32 + nl;
        const int xr = 64 + q;
        float e = e_part[0][idx] + e_part[1][idx] + e_part[2][idx] + e_part[3][idx]
                + e_part[0][xr]  + e_part[1][xr]  + e_part[2][xr]  + e_part[3][xr];
        e = (e > 0.f) ? e : 0.2f * e;
        float mx = e;
#pragma unroll
        for (int m = 16; m >= 1; m >>= 1) mx = fmaxf(mx, __shfl_xor(mx, m, 32));
        float ex = __expf(e - mx);
        float sum = ex;
#pragma unroll
        for (int m = 16; m >= 1; m >>= 1) sum += __shfl_xor(sum, m, 32);
        att = ex / sum;
    }

    // WcT panel loads issue here — latency hides under aggregation
    bf16x8 bff[4][4];
#pragma unroll
    for (int c4 = 0; c4 < 4; ++c4)
#pragma unroll
        for (int ks = 0; ks < 4; ++ks)
            bff[c4][ks] = *(const bf16x8*)(WcT + (size_t)(w * 64 + c4 * 16 + lr) * 128 + ks * 32 + lg * 8);

    // ---- aggregation: lane owns one d (f32 reads); 4 partial chains ----
    {
        const int d = dh * 64 + l;                // wave's d-half; l spans 64 d's
        const int dcb = 4 * d;
        float ag0 = 0.f, ag1 = 0.f, ag2 = 0.f, ag3 = 0.f;
#pragma unroll
        for (int n4 = 0; n4 < 8; ++n4) {
#pragma unroll
            for (int pp = 0; pp < 4; ++pp) {
                const int n = n4 * 4 + pp;
                float wv = __shfl(att, n);        // lane n holds att[n] (both halves)
                const int row = q * 32 + n;
                float v = *(const float*)(nb + row * 512 + (dcb ^ ((row & 15) << 5)));
                if (pp == 0) ag0 = fmaf(wv, v, ag0);
                else if (pp == 1) ag1 = fmaf(wv, v, ag1);
                else if (pp == 2) ag2 = fmaf(wv, v, ag2);
                else ag3 = fmaf(wv, v, ag3);
            }
        }
        float ag = (ag0 + ag1) + (ag2 + ag3);
        const int arow = 2 + q;                   // agg rows 2..3 of xagg
        *(__bf16*)(xb + arow * 256 + ((2 * d) ^ ((arow & 7) << 4))) = (__bf16)ag;
    }
    __syncthreads();                              // B3: agg rows visible

    // ---- final: [x0,x1,agg0,agg1,junk](16x128) @ WcT^T, masked f32 store ----
    {
        bf16x8 af[4];
#pragma unroll
        for (int ks = 0; ks < 4; ++ks)
            af[ks] = *(const bf16x8*)(xb + lr * 256 + ((ks * 64 + lg * 16) ^ ((lr & 7) << 4)));
        f32x4 acc[4];
#pragma unroll
        for (int c4 = 0; c4 < 4; ++c4) acc[c4] = (f32x4){0.f, 0.f, 0.f, 0.f};
#pragma unroll
        for (int ks = 0; ks < 4; ++ks)
#pragma unroll
            for (int c4 = 0; c4 < 4; ++c4)
                acc[c4] = __builtin_amdgcn_mfma_f32_16x16x32_bf16(af[ks], bff[c4][ks], acc[c4], 0, 0, 0);
        if (lg == 0) {                            // C rows 0..3 live in lg==0 lanes
#pragma unroll
            for (int c4 = 0; c4 < 4; ++c4) {
                int col = w * 64 + c4 * 16 + lr;
                if (col < 128) {                  // x rows 0,1 -> out cols 0..127
                    out[(size_t)(b0 + 0) * 256 + col] = fmaxf(acc[c4][0], 0.f);
                    out[(size_t)(b0 + 1) * 256 + col] = fmaxf(acc[c4][1], 0.f);
                } else {                          // agg rows 2,3 -> out cols 128..255
                    out[(size_t)(b0 + 0) * 256 + col] = fmaxf(acc[c4][2], 0.f);
                    out[(size_t)(b0 + 1) * 256 + col] = fmaxf(acc[c4][3], 0.f);
                }
            }
        }
    }
}

extern "C" void kernel_launch(void* const* d_in, const int* in_sizes, int n_in,
                              void* d_out, int out_size, void* d_ws, size_t ws_size,
                              hipStream_t stream) {
    const float* x    = (const float*)d_in[0];
    const float* nb   = (const float*)d_in[1];
    const float* Watt = (const float*)d_in[2];
    const float* Wfcx = (const float*)d_in[3];
    const float* Wfcn = (const float*)d_in[4];
    const float* a    = (const float*)d_in[5];
    __bf16* WaT = (__bf16*)d_ws;
    __bf16* WcT = WaT + 32768;
    float* o = (float*)d_out;

    prep_weights<<<256, 256, 0, stream>>>(Watt, Wfcx, Wfcn, WaT, WcT);
    gat_fused<<<BB / MB, 256, 0, stream>>>(x, nb, a, WaT, WcT, o);
}

// Round 12
// 126.622 us; speedup vs baseline: 1.4768x; 1.4768x over previous
//
#include <hip/hip_runtime.h>
#include <hip/hip_bf16.h>

// GAT attention aggregator, fused. B=20000, N=32, D=128, H=256, O=128.
// R12: R5 skeleton (best: 132.8us) + swapped-operand score matmul.
// mfma(W_frag, R_frag) -> S^T[h, r]: lane&15 = r, so the lrelu(.01)*a
// h-reduction is an in-register scalar sum (3 VALU/elem, no DPP red16
// chain). Coefs a[h] live in 16 regs, rewritten for the peeled x-tile.
// Softmax / aggregation / final matmul / staging verbatim from R5.

#define BB 20000
#define NN 32
#define DD 128
#define HH 256
#define OO 128
#define MB 4
#define ROWS 144         // 128 neib + 4 x (128..131) + 4 agg (132..135) + 8 junk
#define AG0 132

typedef __bf16 bf16x8 __attribute__((ext_vector_type(8)));
typedef __bf16 bf16x4 __attribute__((ext_vector_type(4)));
typedef float f32x4 __attribute__((ext_vector_type(4)));

__global__ void prep_weights(const float* __restrict__ Watt,
                             const float* __restrict__ Wfcx,
                             const float* __restrict__ Wfcn,
                             __bf16* __restrict__ WaT,
                             __bf16* __restrict__ WcT) {
    int idx = blockIdx.x * 256 + threadIdx.x;   // 0..65535
    int half = idx >> 15;
    int j = idx & 32767;
    int c = j >> 7, k = j & 127;
    if (half == 0) {
        WaT[j] = (__bf16)Watt[k * HH + c];       // WaT[h][k] = W_att[k][h]
    } else {
        float wv = (c < OO) ? Wfcx[k * OO + c] : Wfcn[k * OO + (c - OO)];
        WcT[j] = (__bf16)wv;                     // WcT[c][k]
    }
}

__launch_bounds__(256, 4)
__global__ void gat_fused(const float* __restrict__ x,
                          const float* __restrict__ neibs,
                          const float* __restrict__ a,
                          const __bf16* __restrict__ WaT,
                          const __bf16* __restrict__ WcT,
                          float* __restrict__ out) {
    __shared__ __bf16 rowsS[ROWS * 128];         // 36,864 B, XOR-swizzled rows
    __shared__ float e_part[4][ROWS];            //  2,304 B
    __shared__ float att_s[MB][NN];              //    512 B

    const int tid = threadIdx.x;
    const int w   = tid >> 6;      // wave 0..3
    const int l   = tid & 63;
    const int lr  = l & 15;
    const int lg  = l >> 4;
    const int b0  = blockIdx.x * MB;
    char* rbase = (char*)rowsS;

    // staging: row = it*8 + (tid>>5); byte off (row*256 + 2k) ^ ((row&7)<<4)
    const int stbase = (tid >> 5) * 256 + ((8 * (tid & 31)) ^ ((tid >> 5) << 4));
    int abase[4];
#pragma unroll
    for (int ks = 0; ks < 4; ++ks)
        abase[ks] = lr * 256 + ((ks * 64 + lg * 16) ^ ((lr & 7) << 4));

    // ---- stage 128 neib rows + 4 x rows into swizzled LDS as bf16 (R5) ----
    {
        const float4* np4 = (const float4*)(neibs + (size_t)b0 * NN * DD);
#pragma unroll
        for (int it = 0; it < 16; ++it) {
            float4 v = np4[it * 256 + tid];
            bf16x4 s = { (__bf16)v.x, (__bf16)v.y, (__bf16)v.z, (__bf16)v.w };
            *(bf16x4*)(rbase + stbase + it * 2048) = s;
        }
        if (tid < 128) {   // x rows 128..131
            float4 v = ((const float4*)(x + (size_t)b0 * DD))[tid];
            bf16x4 s = { (__bf16)v.x, (__bf16)v.y, (__bf16)v.z, (__bf16)v.w };
            *(bf16x4*)(rbase + stbase + 32768) = s;
        }
    }

    // ---- W_att panel (A-operand now) + a-coefs for neighbor rows ----
    bf16x8 bw[4][4];
    float cN[4][4];
#pragma unroll
    for (int c4 = 0; c4 < 4; ++c4) {
        int col = (w * 4 + c4) * 16 + lr;
#pragma unroll
        for (int ks = 0; ks < 4; ++ks)
            bw[c4][ks] = *(const bf16x8*)(WaT + col * 128 + ks * 32 + lg * 8);
#pragma unroll
        for (int i = 0; i < 4; ++i)
            cN[c4][i] = a[HH + (w * 4 + c4) * 16 + 4 * lg + i];
    }

    __syncthreads();                              // B1: staged rows visible

    // ---- score (swapped): acc = W^T-tile x R-rows = S^T[h, r] ----
    // C layout: row = 4*lg + i = h-local, col = lane&15 = r. Per lane all 16
    // acc elems belong to ONE row r -> scalar ep accumulation, no red16.
#pragma unroll
    for (int rt = 0; rt < 8; ++rt) {
        bf16x8 af[4];
#pragma unroll
        for (int ks = 0; ks < 4; ++ks)
            af[ks] = *(const bf16x8*)(rbase + abase[ks] + rt * 4096);
        f32x4 acc[4];
#pragma unroll
        for (int c4 = 0; c4 < 4; ++c4) acc[c4] = (f32x4){0.f, 0.f, 0.f, 0.f};
#pragma unroll
        for (int ks = 0; ks < 4; ++ks)
#pragma unroll
            for (int c4 = 0; c4 < 4; ++c4)
                acc[c4] = __builtin_amdgcn_mfma_f32_16x16x32_bf16(bw[c4][ks], af[ks], acc[c4], 0, 0, 0);
        float ep = 0.f;
#pragma unroll
        for (int c4 = 0; c4 < 4; ++c4)
#pragma unroll
            for (int i = 0; i < 4; ++i) {
                float v = acc[c4][i];
                ep = fmaf(cN[c4][i], fmaxf(v, 0.01f * v), ep);
            }
        ep += __shfl_xor(ep, 16);
        ep += __shfl_xor(ep, 32);
        if (l < 16) e_part[w][rt * 16 + l] = ep;
    }
    // peeled x-tile (rows 128..143): rewrite coefs with a[:H]
    {
#pragma unroll
        for (int c4 = 0; c4 < 4; ++c4)
#pragma unroll
            for (int i = 0; i < 4; ++i)
                cN[c4][i] = a[(w * 4 + c4) * 16 + 4 * lg + i];
        bf16x8 af[4];
#pragma unroll
        for (int ks = 0; ks < 4; ++ks)
            af[ks] = *(const bf16x8*)(rbase + abase[ks] + 32768);
        f32x4 acc[4];
#pragma unroll
        for (int c4 = 0; c4 < 4; ++c4) acc[c4] = (f32x4){0.f, 0.f, 0.f, 0.f};
#pragma unroll
        for (int ks = 0; ks < 4; ++ks)
#pragma unroll
            for (int c4 = 0; c4 < 4; ++c4)
                acc[c4] = __builtin_amdgcn_mfma_f32_16x16x32_bf16(bw[c4][ks], af[ks], acc[c4], 0, 0, 0);
        float ep = 0.f;
#pragma unroll
        for (int c4 = 0; c4 < 4; ++c4)
#pragma unroll
            for (int i = 0; i < 4; ++i) {
                float v = acc[c4][i];
                ep = fmaf(cN[c4][i], fmaxf(v, 0.01f * v), ep);
            }
        ep += __shfl_xor(ep, 16);
        ep += __shfl_xor(ep, 32);
        if (l < 16) e_part[w][128 + l] = ep;      // rows 128..143 (132+ junk, unread)
    }
    __syncthreads();                              // B2: e_part complete

    // ---- combine e, lrelu(0.2), softmax over 32 neighbors (threads 0..127) ----
    if (tid < 128) {
        const int bloc = tid >> 5;
        const int nloc = tid & 31;
        float sn = e_part[0][tid] + e_part[1][tid] + e_part[2][tid] + e_part[3][tid];
        float sx = e_part[0][128 + bloc] + e_part[1][128 + bloc] +
                   e_part[2][128 + bloc] + e_part[3][128 + bloc];
        float e = sx + sn;
        e = (e > 0.f) ? e : 0.2f * e;
        float mx = e;
#pragma unroll
        for (int m = 16; m >= 1; m >>= 1) mx = fmaxf(mx, __shfl_xor(mx, m, 32));
        float ex = __expf(e - mx);
        float sum = ex;
#pragma unroll
        for (int m = 16; m >= 1; m >>= 1) sum += __shfl_xor(sum, m, 32);
        att_s[bloc][nloc] = ex / sum;
    }
    __syncthreads();                              // B3: att_s ready

    // ---- WcT panel loads issue here; latency hides under aggregation ----
    bf16x8 bff[4][4];
#pragma unroll
    for (int c4 = 0; c4 < 4; ++c4)
#pragma unroll
        for (int ks = 0; ks < 4; ++ks)
            bff[c4][ks] = *(const bf16x8*)(WcT + ((w * 4 + c4) * 16 + lr) * 128 + ks * 32 + lg * 8);

    // ---- aggregation: wave w = node w; half-waves take even/odd neighbors ----
    {
        const int half = l >> 5, li = l & 31;
        const int agbase = w * 8192 + 256 * half + ((8 * li) ^ (half << 4));
        float ag[4] = {0.f, 0.f, 0.f, 0.f};
#pragma unroll
        for (int i = 0; i < 16; ++i) {
            float wv = att_s[w][2 * i + half];
            bf16x4 v = *(const bf16x4*)(rbase + (agbase ^ ((2 * i & 7) << 4)) + 512 * i);
#pragma unroll
            for (int j = 0; j < 4; ++j) ag[j] = fmaf(wv, (float)v[j], ag[j]);
        }
#pragma unroll
        for (int j = 0; j < 4; ++j) ag[j] += __shfl_xor(ag[j], 32);
        if (half == 0) {
            int row = AG0 + w;                    // row&7 = 4+w
            int off = row * 256 + ((8 * li) ^ ((row & 7) << 4));
            bf16x4 s = { (__bf16)ag[0], (__bf16)ag[1], (__bf16)ag[2], (__bf16)ag[3] };
            *(bf16x4*)(rbase + off) = s;
        }
    }
    __syncthreads();                              // B4: agg rows visible

    // ---- final matmul: [x;agg;junk](16x128) @ WcT^T(128x256), masked store ----
    {
        bf16x8 af[4];
#pragma unroll
        for (int ks = 0; ks < 4; ++ks)
            af[ks] = *(const bf16x8*)(rbase + abase[ks] + 32768);  // rows 128+lr
        f32x4 acc[4];
#pragma unroll
        for (int c4 = 0; c4 < 4; ++c4) acc[c4] = (f32x4){0.f, 0.f, 0.f, 0.f};
#pragma unroll
        for (int ks = 0; ks < 4; ++ks)
#pragma unroll
            for (int c4 = 0; c4 < 4; ++c4)
                acc[c4] = __builtin_amdgcn_mfma_f32_16x16x32_bf16(af[ks], bff[c4][ks], acc[c4], 0, 0, 0);
#pragma unroll
        for (int c4 = 0; c4 < 4; ++c4) {
            int col = (w * 4 + c4) * 16 + lr;
#pragma unroll
            for (int reg = 0; reg < 4; ++reg) {
                int i = lg * 4 + reg;             // C row: 0..3 = x, 4..7 = agg
                bool doit = (col < 128) ? (i < 4) : (i >= 4 && i < 8);
                if (doit) {
                    float v = fmaxf(acc[c4][reg], 0.f);
                    out[(size_t)(b0 + (i & 3)) * 256 + col] = v;
                }
            }
        }
    }
}

extern "C" void kernel_launch(void* const* d_in, const int* in_sizes, int n_in,
                              void* d_out, int out_size, void* d_ws, size_t ws_size,
                              hipStream_t stream) {
    const float* x    = (const float*)d_in[0];
    const float* nb   = (const float*)d_in[1];
    const float* Watt = (const float*)d_in[2];
    const float* Wfcx = (const float*)d_in[3];
    const float* Wfcn = (const float*)d_in[4];
    const float* a    = (const float*)d_in[5];
    __bf16* WaT = (__bf16*)d_ws;
    __bf16* WcT = WaT + 32768;
    float* o = (float*)d_out;

    prep_weights<<<256, 256, 0, stream>>>(Watt, Wfcx, Wfcn, WaT, WcT);
    gat_fused<<<BB / MB, 256, 0, stream>>>(x, nb, a, WaT, WcT, o);
}

// Round 13
// 125.246 us; speedup vs baseline: 1.4930x; 1.0110x over previous
//
#include <hip/hip_runtime.h>
#include <hip/hip_bf16.h>

// GAT attention aggregator, fused. B=20000, N=32, D=128, H=256, O=128.
// R13 = R12 (best: 126.6us) + round-1 phase-desync stagger. Theory: identical
// block durations keep co-resident blocks phase-aligned (staging convoys with
// staging), so phases serialize chip-wide. A one-time pseudo-random 0..3us
// sleep for the first-round blocks (bid<1280) breaks the symmetry; equal
// durations then preserve the stagger for all subsequent rounds.

#define BB 20000
#define NN 32
#define DD 128
#define HH 256
#define OO 128
#define MB 4
#define ROWS 144         // 128 neib + 4 x (128..131) + 4 agg (132..135) + 8 junk
#define AG0 132

typedef __bf16 bf16x8 __attribute__((ext_vector_type(8)));
typedef __bf16 bf16x4 __attribute__((ext_vector_type(4)));
typedef float f32x4 __attribute__((ext_vector_type(4)));

__global__ void prep_weights(const float* __restrict__ Watt,
                             const float* __restrict__ Wfcx,
                             const float* __restrict__ Wfcn,
                             __bf16* __restrict__ WaT,
                             __bf16* __restrict__ WcT) {
    int idx = blockIdx.x * 256 + threadIdx.x;   // 0..65535
    int half = idx >> 15;
    int j = idx & 32767;
    int c = j >> 7, k = j & 127;
    if (half == 0) {
        WaT[j] = (__bf16)Watt[k * HH + c];       // WaT[h][k] = W_att[k][h]
    } else {
        float wv = (c < OO) ? Wfcx[k * OO + c] : Wfcn[k * OO + (c - OO)];
        WcT[j] = (__bf16)wv;                     // WcT[c][k]
    }
}

__launch_bounds__(256, 4)
__global__ void gat_fused(const float* __restrict__ x,
                          const float* __restrict__ neibs,
                          const float* __restrict__ a,
                          const __bf16* __restrict__ WaT,
                          const __bf16* __restrict__ WcT,
                          float* __restrict__ out) {
    __shared__ __bf16 rowsS[ROWS * 128];         // 36,864 B, XOR-swizzled rows
    __shared__ float e_part[4][ROWS];            //  2,304 B
    __shared__ float att_s[MB][NN];              //    512 B

    // ---- round-1 desync: stagger the 4 co-resident blocks per CU ----
    {
        const unsigned bid = blockIdx.x;
        if (bid < 1280) {
            const unsigned k = (bid * 2654435761u) >> 30;   // 0..3 pseudo-random
            for (unsigned i = 0; i < k; ++i)
                __builtin_amdgcn_s_sleep(40);               // ~2560 cy ~= 1.07 us
        }
    }

    const int tid = threadIdx.x;
    const int w   = tid >> 6;      // wave 0..3
    const int l   = tid & 63;
    const int lr  = l & 15;
    const int lg  = l >> 4;
    const int b0  = blockIdx.x * MB;
    char* rbase = (char*)rowsS;

    // staging: row = it*8 + (tid>>5); byte off (row*256 + 2k) ^ ((row&7)<<4)
    const int stbase = (tid >> 5) * 256 + ((8 * (tid & 31)) ^ ((tid >> 5) << 4));
    int abase[4];
#pragma unroll
    for (int ks = 0; ks < 4; ++ks)
        abase[ks] = lr * 256 + ((ks * 64 + lg * 16) ^ ((lr & 7) << 4));

    // ---- stage 128 neib rows + 4 x rows into swizzled LDS as bf16 ----
    {
        const float4* np4 = (const float4*)(neibs + (size_t)b0 * NN * DD);
#pragma unroll
        for (int it = 0; it < 16; ++it) {
            float4 v = np4[it * 256 + tid];
            bf16x4 s = { (__bf16)v.x, (__bf16)v.y, (__bf16)v.z, (__bf16)v.w };
            *(bf16x4*)(rbase + stbase + it * 2048) = s;
        }
        if (tid < 128) {   // x rows 128..131
            float4 v = ((const float4*)(x + (size_t)b0 * DD))[tid];
            bf16x4 s = { (__bf16)v.x, (__bf16)v.y, (__bf16)v.z, (__bf16)v.w };
            *(bf16x4*)(rbase + stbase + 32768) = s;
        }
    }

    // ---- W_att panel (A-operand) + a-coefs for neighbor rows ----
    bf16x8 bw[4][4];
    float cN[4][4];
#pragma unroll
    for (int c4 = 0; c4 < 4; ++c4) {
        int col = (w * 4 + c4) * 16 + lr;
#pragma unroll
        for (int ks = 0; ks < 4; ++ks)
            bw[c4][ks] = *(const bf16x8*)(WaT + col * 128 + ks * 32 + lg * 8);
#pragma unroll
        for (int i = 0; i < 4; ++i)
            cN[c4][i] = a[HH + (w * 4 + c4) * 16 + 4 * lg + i];
    }

    __syncthreads();                              // B1: staged rows visible

    // ---- score (swapped): acc = W^T-tile x R-rows = S^T[h, r] ----
#pragma unroll
    for (int rt = 0; rt < 8; ++rt) {
        bf16x8 af[4];
#pragma unroll
        for (int ks = 0; ks < 4; ++ks)
            af[ks] = *(const bf16x8*)(rbase + abase[ks] + rt * 4096);
        f32x4 acc[4];
#pragma unroll
        for (int c4 = 0; c4 < 4; ++c4) acc[c4] = (f32x4){0.f, 0.f, 0.f, 0.f};
#pragma unroll
        for (int ks = 0; ks < 4; ++ks)
#pragma unroll
            for (int c4 = 0; c4 < 4; ++c4)
                acc[c4] = __builtin_amdgcn_mfma_f32_16x16x32_bf16(bw[c4][ks], af[ks], acc[c4], 0, 0, 0);
        float ep = 0.f;
#pragma unroll
        for (int c4 = 0; c4 < 4; ++c4)
#pragma unroll
            for (int i = 0; i < 4; ++i) {
                float v = acc[c4][i];
                ep = fmaf(cN[c4][i], fmaxf(v, 0.01f * v), ep);
            }
        ep += __shfl_xor(ep, 16);
        ep += __shfl_xor(ep, 32);
        if (l < 16) e_part[w][rt * 16 + l] = ep;
    }
    // peeled x-tile (rows 128..143): rewrite coefs with a[:H]
    {
#pragma unroll
        for (int c4 = 0; c4 < 4; ++c4)
#pragma unroll
            for (int i = 0; i < 4; ++i)
                cN[c4][i] = a[(w * 4 + c4) * 16 + 4 * lg + i];
        bf16x8 af[4];
#pragma unroll
        for (int ks = 0; ks < 4; ++ks)
            af[ks] = *(const bf16x8*)(rbase + abase[ks] + 32768);
        f32x4 acc[4];
#pragma unroll
        for (int c4 = 0; c4 < 4; ++c4) acc[c4] = (f32x4){0.f, 0.f, 0.f, 0.f};
#pragma unroll
        for (int ks = 0; ks < 4; ++ks)
#pragma unroll
            for (int c4 = 0; c4 < 4; ++c4)
                acc[c4] = __builtin_amdgcn_mfma_f32_16x16x32_bf16(bw[c4][ks], af[ks], acc[c4], 0, 0, 0);
        float ep = 0.f;
#pragma unroll
        for (int c4 = 0; c4 < 4; ++c4)
#pragma unroll
            for (int i = 0; i < 4; ++i) {
                float v = acc[c4][i];
                ep = fmaf(cN[c4][i], fmaxf(v, 0.01f * v), ep);
            }
        ep += __shfl_xor(ep, 16);
        ep += __shfl_xor(ep, 32);
        if (l < 16) e_part[w][128 + l] = ep;      // rows 128..143 (132+ junk, unread)
    }
    __syncthreads();                              // B2: e_part complete

    // ---- combine e, lrelu(0.2), softmax over 32 neighbors (threads 0..127) ----
    if (tid < 128) {
        const int bloc = tid >> 5;
        const int nloc = tid & 31;
        float sn = e_part[0][tid] + e_part[1][tid] + e_part[2][tid] + e_part[3][tid];
        float sx = e_part[0][128 + bloc] + e_part[1][128 + bloc] +
                   e_part[2][128 + bloc] + e_part[3][128 + bloc];
        float e = sx + sn;
        e = (e > 0.f) ? e : 0.2f * e;
        float mx = e;
#pragma unroll
        for (int m = 16; m >= 1; m >>= 1) mx = fmaxf(mx, __shfl_xor(mx, m, 32));
        float ex = __expf(e - mx);
        float sum = ex;
#pragma unroll
        for (int m = 16; m >= 1; m >>= 1) sum += __shfl_xor(sum, m, 32);
        att_s[bloc][nloc] = ex / sum;
    }
    __syncthreads();                              // B3: att_s ready

    // ---- WcT panel loads issue here; latency hides under aggregation ----
    bf16x8 bff[4][4];
#pragma unroll
    for (int c4 = 0; c4 < 4; ++c4)
#pragma unroll
        for (int ks = 0; ks < 4; ++ks)
            bff[c4][ks] = *(const bf16x8*)(WcT + ((w * 4 + c4) * 16 + lr) * 128 + ks * 32 + lg * 8);

    // ---- aggregation: wave w = node w; half-waves take even/odd neighbors ----
    {
        const int half = l >> 5, li = l & 31;
        const int agbase = w * 8192 + 256 * half + ((8 * li) ^ (half << 4));
        float ag[4] = {0.f, 0.f, 0.f, 0.f};
#pragma unroll
        for (int i = 0; i < 16; ++i) {
            float wv = att_s[w][2 * i + half];
            bf16x4 v = *(const bf16x4*)(rbase + (agbase ^ ((2 * i & 7) << 4)) + 512 * i);
#pragma unroll
            for (int j = 0; j < 4; ++j) ag[j] = fmaf(wv, (float)v[j], ag[j]);
        }
#pragma unroll
        for (int j = 0; j < 4; ++j) ag[j] += __shfl_xor(ag[j], 32);
        if (half == 0) {
            int row = AG0 + w;                    // row&7 = 4+w
            int off = row * 256 + ((8 * li) ^ ((row & 7) << 4));
            bf16x4 s = { (__bf16)ag[0], (__bf16)ag[1], (__bf16)ag[2], (__bf16)ag[3] };
            *(bf16x4*)(rbase + off) = s;
        }
    }
    __syncthreads();                              // B4: agg rows visible

    // ---- final matmul: [x;agg;junk](16x128) @ WcT^T(128x256), masked store ----
    {
        bf16x8 af[4];
#pragma unroll
        for (int ks = 0; ks < 4; ++ks)
            af[ks] = *(const bf16x8*)(rbase + abase[ks] + 32768);  // rows 128+lr
        f32x4 acc[4];
#pragma unroll
        for (int c4 = 0; c4 < 4; ++c4) acc[c4] = (f32x4){0.f, 0.f, 0.f, 0.f};
#pragma unroll
        for (int ks = 0; ks < 4; ++ks)
#pragma unroll
            for (int c4 = 0; c4 < 4; ++c4)
                acc[c4] = __builtin_amdgcn_mfma_f32_16x16x32_bf16(af[ks], bff[c4][ks], acc[c4], 0, 0, 0);
#pragma unroll
        for (int c4 = 0; c4 < 4; ++c4) {
            int col = (w * 4 + c4) * 16 + lr;
#pragma unroll
            for (int reg = 0; reg < 4; ++reg) {
                int i = lg * 4 + reg;             // C row: 0..3 = x, 4..7 = agg
                bool doit = (col < 128) ? (i < 4) : (i >= 4 && i < 8);
                if (doit) {
                    float v = fmaxf(acc[c4][reg], 0.f);
                    out[(size_t)(b0 + (i & 3)) * 256 + col] = v;
                }
            }
        }
    }
}

extern "C" void kernel_launch(void* const* d_in, const int* in_sizes, int n_in,
                              void* d_out, int out_size, void* d_ws, size_t ws_size,
                              hipStream_t stream) {
    const float* x    = (const float*)d_in[0];
    const float* nb   = (const float*)d_in[1];
    const float* Watt = (const float*)d_in[2];
    const float* Wfcx = (const float*)d_in[3];
    const float* Wfcn = (const float*)d_in[4];
    const float* a    = (const float*)d_in[5];
    __bf16* WaT = (__bf16*)d_ws;
    __bf16* WcT = WaT + 32768;
    float* o = (float*)d_out;

    prep_weights<<<256, 256, 0, stream>>>(Watt, Wfcx, Wfcn, WaT, WcT);
    gat_fused<<<BB / MB, 256, 0, stream>>>(x, nb, a, WaT, WcT, o);
}